// Round 7
// baseline (210.626 us; speedup 1.0000x reference)
//
#include <hip/hip_runtime.h>

// ZeroPad2d: in [32,2048,2048] f32 -> out [32,2050,2050] f32, pad=1.
// R7 = R4 (1 row / 256-thread block, misaligned loads + 16B-ALIGNED stores)
// with a fully BRANCH-FREE bulk body:
//   - parity p = (h&1)^1 makes body = out+s+2p 16B-aligned; loads come from
//     ls = src + 2p - 1, which is IN BOUNDS for every row and chunk
//     (p=1 rows have h<=2046 so src+2048 = next row's first element exists;
//      p=0 rows have h>=1 so src-1 = previous row's last element exists)
//   - both chunk loads issue unconditionally (2 in flight per thread);
//     the two pad-zero elements are patched via cndmask (no branch)
//   - per-row leftover 2 floats are handled by 256 dedicated branchless
//     blocks (1 row per thread, f32x2 8B-aligned stores)
//   - 64 blocks zero the top/bottom pad rows
// Every output element is written on every call (harness does not re-poison).

#define CH 32
#define H  2048
#define HPAD 2050
#define WPAD 2050
#define NROWS (CH * H)        // 65536
#define PAD_BLOCKS 64
#define LEFT_BLOCKS 256       // 65536 rows / 256 threads

typedef float f32x4 __attribute__((ext_vector_type(4)));
typedef float f32x2 __attribute__((ext_vector_type(2)));

__global__ __launch_bounds__(256) void zeropad_rows(const float* __restrict__ in,
                                                    float* __restrict__ out) {
    const unsigned bid = blockIdx.x;
    const unsigned t   = threadIdx.x;

    if (bid < NROWS) {
        // ---------- bulk: one input row, branch-free ----------
        const unsigned c = bid >> 11;            // row / 2048
        const unsigned h = bid & 2047u;          // row % 2048
        const float* src = in + ((size_t)bid << 11);
        const size_t  s  = (size_t)(c * HPAD + h + 1u) * WPAD;  // row start
        const unsigned p = (h & 1u) ^ 1u;        // h even -> s%4==2 -> p=1
        float* body      = out + s + 2u * p;     // 16B-aligned
        const float* ls  = src + (2 * (int)p - 1);  // in-bounds for all rows

        f32x4 a, b;                              // two independent loads in flight
        __builtin_memcpy(&a, ls + 4u * t,           16);   // 4B-aligned 16B load
        __builtin_memcpy(&b, ls + 4u * t + 1024u,   16);

        // pad-zero patches (v_cndmask, no branch):
        a[0] = ((p | t) == 0u) ? 0.f : a[0];             // p==0, chunk k=0:   x=0
        b[3] = (p == 1u && t == 255u) ? 0.f : b[3];      // p==1, chunk k=511: x=2049

        *(f32x4*)(body + 4u * t)          = a;           // 16B-aligned stores
        *(f32x4*)(body + 4u * t + 1024u)  = b;
    } else if (bid < NROWS + PAD_BLOCKS) {
        // ---------- top/bottom zero pad rows: 32 channels x 2 rows ----------
        const unsigned idx = bid - NROWS;        // 0..63
        const unsigned c   = idx >> 1;
        const unsigned y   = (idx & 1u) ? (HPAD - 1u) : 0u;
        float* dst = out + (size_t)(c * HPAD + y) * WPAD;    // even -> 8B-aligned

        const f32x2 z2 = (f32x2)0.f;
        #pragma unroll
        for (int kk = 0; kk < 4; ++kk) {
            const unsigned k = t + 256u * kk;                // 0..1023
            *(f32x2*)(dst + 2u * k) = z2;                    // 8B-aligned store
        }
        if (t == 0u) { dst[2048] = 0.f; dst[2049] = 0.f; }
    } else {
        // ---------- per-row leftover 2 floats, branchless, 1 row/thread ----------
        const unsigned r = (bid - NROWS - PAD_BLOCKS) * 256u + t;   // 0..65535
        const unsigned c = r >> 11;
        const unsigned h = r & 2047u;
        const float* src = in + ((size_t)r << 11);
        const size_t  s  = (size_t)(c * HPAD + h + 1u) * WPAD;
        const unsigned p = (h & 1u) ^ 1u;

        // p==0: dstrow[2048..2049] = {src[2047], 0}
        // p==1: dstrow[0..1]       = {0, src[0]}
        const float xv = src[p ? 0u : 2047u];
        f32x2 v;
        v[0] = p ? 0.f : xv;
        v[1] = p ? xv  : 0.f;
        *(f32x2*)(out + s + (p ? 0u : 2048u)) = v;           // 8B-aligned
    }
}

extern "C" void kernel_launch(void* const* d_in, const int* in_sizes, int n_in,
                              void* d_out, int out_size, void* d_ws, size_t ws_size,
                              hipStream_t stream) {
    const float* in = (const float*)d_in[0];
    float* out = (float*)d_out;
    const int blocks = NROWS + PAD_BLOCKS + LEFT_BLOCKS;     // 65856
    zeropad_rows<<<blocks, 256, 0, stream>>>(in, out);
}

// Round 8
// 189.054 us; speedup vs baseline: 1.1141x; 1.1141x over previous
//
#include <hip/hip_runtime.h>

// ZeroPad2d: in [32,2048,2048] f32 -> out [32,2050,2050] f32, pad=1.
// R8: pure-dword streaming. Every access is a 4B dword -> NEVER misaligned,
// no lane ever straddles a 64B line (R4's 16B loads split every 4th lane into
// two TA sub-transactions). Consecutive lanes hit consecutive dwords, so the
// coalescer builds the same full-line requests as a float4 kernel.
//   - grid (2050, 32): one 256-thread block per OUTPUT row; no divisions
//   - interior row: 8 independent dword loads batched, then 8 dword stores
//     (the +1 output shift is pure addressing, not alignment)
//   - pad rows (y=0, y=2049): 8 dword zero-stores (block-uniform branch)
//   - lanes 0/1 write the row's left/right pad zeros
// No shuffles, no LDS, no side blocks (R6/R7 lesson: realignment machinery
// costs more than it saves). Every output element written every call.

#define H 2048
#define W 2048
#define HPAD 2050
#define WPAD 2050

__global__ __launch_bounds__(256) void zeropad_dw(const float* __restrict__ in,
                                                  float* __restrict__ out) {
    const unsigned y = blockIdx.x;     // 0..2049 (padded row)
    const unsigned c = blockIdx.y;     // 0..31   (channel)
    const unsigned t = threadIdx.x;    // 0..255
    float* orow = out + ((size_t)c * HPAD + y) * WPAD;

    if (y >= 1u && y <= (unsigned)H) {
        // interior row: out[y][1..2048] = in[y-1][0..2047]
        const float* srow = in + ((size_t)c * H + (y - 1u)) * W;
        float v[8];
        #pragma unroll
        for (int j = 0; j < 8; ++j)            // 8 independent coalesced loads
            v[j] = srow[t + 256u * j];
        #pragma unroll
        for (int j = 0; j < 8; ++j)            // 8 coalesced dword stores
            orow[1u + t + 256u * j] = v[j];
        if (t < 2u) orow[t ? (WPAD - 1u) : 0u] = 0.f;   // left/right pad
    } else {
        // top/bottom pad row: 2050 zeros
        #pragma unroll
        for (int j = 0; j < 8; ++j)
            orow[t + 256u * j] = 0.f;          // covers 0..2047
        if (t < 2u) orow[2048u + t] = 0.f;     // covers 2048..2049
    }
}

extern "C" void kernel_launch(void* const* d_in, const int* in_sizes, int n_in,
                              void* d_out, int out_size, void* d_ws, size_t ws_size,
                              hipStream_t stream) {
    const float* in = (const float*)d_in[0];
    float* out = (float*)d_out;
    dim3 grid(HPAD, 32);                       // 2050 rows x 32 channels
    zeropad_dw<<<grid, 256, 0, stream>>>(in, out);
}